// Round 17
// baseline (222.635 us; speedup 1.0000x reference)
//
#include <hip/hip_runtime.h>
#include <hip/hip_fp16.h>

#define NN 50000
#define NE 800000
#define SLN 6250        // NN/8 nodes per XCD bin
#define CAP 64          // csr slots per node (Poisson(16): P(deg>=64) ~ 1e-18)
#define BCAP 106496     // pair capacity per bin
constexpr float EPSV = 1e-5f;

typedef __attribute__((ext_vector_type(8))) short short8;
typedef __attribute__((ext_vector_type(4))) float f32x4;

__device__ __forceinline__ float bf2f(unsigned short u) {
    return __uint_as_float(((unsigned int)u) << 16);
}
__device__ __forceinline__ unsigned short f2bf(float f) {
    unsigned int x = __float_as_uint(f);
    return (unsigned short)((x + 0x7FFFu + ((x >> 16) & 1u)) >> 16);
}
// f32 -> fp8 e5m2 (via fp16, round-to-nearest-even on the mantissa drop)
__device__ __forceinline__ unsigned char f2e5(float f) {
    unsigned short h = __half_as_ushort(__float2half(f));
    unsigned short r = h + 0x7F + ((h >> 8) & 1);
    return (unsigned char)(r >> 8);
}
// accumulate 16 fp8(e5m2) packed in a uint4 into a[0..15]
__device__ __forceinline__ void acc16(float* a, uint4 u) {
#pragma unroll
    for (int q = 0; q < 4; q++) {
        unsigned int x = (q == 0) ? u.x : (q == 1) ? u.y : (q == 2) ? u.z : u.w;
        unsigned int h01 = ((x << 8) & 0xFF00u) | ((x << 16) & 0xFF000000u);
        unsigned int h23 = ((x >> 8) & 0xFF00u) | (x & 0xFF000000u);
        __half2 p01 = *(__half2*)&h01, p23 = *(__half2*)&h23;
        float2 f01 = __half22float2(p01), f23 = __half22float2(p23);
        a[q * 4 + 0] += f01.x; a[q * 4 + 1] += f01.y;
        a[q * 4 + 2] += f23.x; a[q * 4 + 3] += f23.y;
    }
}

// ---------------- scatter: blocks on XCD k consume bin k ----------------
__global__ __launch_bounds__(256) void k_scatter2(const int2* __restrict__ binBuf,
                                                  const int* __restrict__ binCnt,
                                                  int* __restrict__ cnt,
                                                  int* __restrict__ csr) {
    int bin = blockIdx.x & 7;
    int lb = blockIdx.x >> 3;
    int n = binCnt[bin];
    const int2* buf = binBuf + (size_t)bin * BCAP;
    for (int i = lb * 256 + threadIdx.x; i < n; i += 128 * 256) {
        int2 p = buf[i];
        int slot = atomicAdd(&cnt[p.x], 1);
        csr[p.x * CAP + slot] = p.y;
    }
}

// ---------------- prep bodies ----------------
__device__ void prep1_body(int t, const float* Wp, const float* bp, const float* W1l,
                           const float* b1l, const float* W1r, const float* g, const float* b,
                           const float* m, const float* v, unsigned short* Wf, float* c) {
    int lane = t & 63, f = (t >> 6) & 3, kt = (t >> 8) & 7;
    int nb = t >> 11;
    int col = nb * 64 + f * 16 + (lane & 15);
    int k0 = kt * 32 + (lane >> 4) * 8;
    float A = g[col] * rsqrtf(v[col] + EPSV);
    unsigned short* o = Wf + (size_t)t * 8;
    for (int j = 0; j < 8; j++) {
        int k = k0 + j;
        float w;
        if (k < 128) w = W1l[k * 256 + col] * A;
        else         w = W1r[(k - 128) * 256 + col] * A + Wp[(k - 128) * 256 + col];
        o[j] = f2bf(w);
    }
    if (t < 256) {
        float At = g[t] * rsqrtf(v[t] + EPSV);
        c[t] = b1l[t] * At + (b[t] - m[t] * At) + bp[t];
    }
}

__device__ void prep2_body(int t, const float* Wsk, const float* bsk, const float* W2l,
                           const float* b2l, const float* W2r, const float* g, const float* b,
                           const float* m, const float* v, unsigned short* Wf, float* c) {
    int lane = t & 63, f = (t >> 6) & 3, kt = (t >> 8) & 7, nb = t >> 11;
    int col = nb * 64 + f * 16 + (lane & 15);
    int k0 = kt * 32 + (lane >> 4) * 8;
    unsigned short* o = Wf + (size_t)t * 8;
    if (col < 128) {
        float A = g[col] * rsqrtf(v[col] + EPSV);
        for (int j = 0; j < 8; j++) o[j] = f2bf(W2l[(k0 + j) * 128 + col] * A);
    } else {
        int cc = col - 128;
        float A = g[cc] * rsqrtf(v[cc] + EPSV);
        for (int j = 0; j < 8; j++)
            o[j] = f2bf(W2r[(k0 + j) * 128 + cc] * A + Wsk[(k0 + j) * 128 + cc]);
    }
    if (t < 128) {
        float At = g[t] * rsqrtf(v[t] + EPSV);
        c[t] = b2l[t] * At + (b[t] - m[t] * At) + bsk[t];
    }
}

__device__ void prep3_body(int t, const float* W3l, const float* b3l, const float* W3r,
                           unsigned short* Wf, float* c) {
    int lane = t & 63, f = (t >> 6) & 3, kt = (t >> 8) & 3, nb = t >> 10;
    int col = nb * 64 + f * 16 + (lane & 15);
    int k0 = kt * 32 + (lane >> 4) * 8;
    unsigned short* o = Wf + (size_t)t * 8;
    if (col < 64) {
        for (int j = 0; j < 8; j++) o[j] = f2bf(W3l[(k0 + j) * 64 + col]);
    } else {
        int cc = col - 64;
        for (int j = 0; j < 8; j++) o[j] = f2bf(W3r[(k0 + j) * 64 + cc]);
    }
    if (t < 64) c[t] = b3l[t];
}

// ---------------- fused prep: xcast + cnt zero + weight folding + edge binning ----------------
__global__ void k_prep_fused(const float* x, unsigned short* xcat, unsigned char* xf8,
                             int* cnt, int* binCnt,
                             const int* src, const int* dst, int2* binBuf,
                             const float* Wp, const float* bp,
                             const float* W1l, const float* b1l, const float* W1r,
                             const float* g1, const float* b1, const float* m1, const float* v1,
                             const float* Wsk, const float* bsk,
                             const float* W2l, const float* b2l, const float* W2r,
                             const float* g2, const float* b2, const float* m2, const float* v2,
                             const float* W3l, const float* b3l, const float* W3r,
                             unsigned short* Wf1, unsigned short* Wf2, unsigned short* Wf3,
                             float* c1, float* c2, float* c3) {
    __shared__ int hcnt[8];
    __shared__ int hbase[8];
    int bb = blockIdx.x;
    int tid = threadIdx.x;
    if (bb < 6250) {  // xcast + cnt zeroing
        int i = bb * 256 + tid;
        if (i < NN / 4) ((int4*)cnt)[i] = make_int4(0, 0, 0, 0);
        if (i >= NN * 128 / 4) return;
        int r = i >> 5, c4 = (i & 31) * 4;
        float4 v = ((const float4*)x)[i];
        ushort4 u = make_ushort4(f2bf(v.x), f2bf(v.y), f2bf(v.z), f2bf(v.w));
        *(ushort4*)&xcat[(size_t)r * 256 + 128 + c4] = u;
        uchar4 u8 = make_uchar4(f2e5(v.x), f2e5(v.y), f2e5(v.z), f2e5(v.w));
        *(uchar4*)&xf8[(size_t)r * 128 + c4] = u8;
    } else if (bb < 6282) {
        prep1_body((bb - 6250) * 256 + tid, Wp, bp, W1l, b1l, W1r, g1, b1, m1, v1, Wf1, c1);
    } else if (bb < 6314) {
        prep2_body((bb - 6282) * 256 + tid, Wsk, bsk, W2l, b2l, W2r, g2, b2, m2, v2, Wf2, c2);
    } else if (bb < 6322) {
        prep3_body((bb - 6314) * 256 + tid, W3l, b3l, W3r, Wf3, c3);
    } else {  // edge binning (782 blocks); binCnt pre-zeroed via hipMemsetAsync
        if (tid < 8) hcnt[tid] = 0;
        __syncthreads();
        int q = (bb - 6322) * 256 + tid;
        bool val = q < NE / 4;
        int4 d = make_int4(0, 0, 0, 0), s = make_int4(0, 0, 0, 0);
        int b0 = 0, b1i = 0, b2i = 0, b3i = 0, r0 = 0, r1 = 0, r2 = 0, r3 = 0;
        if (val) {
            d = ((const int4*)dst)[q];
            s = ((const int4*)src)[q];
            b0 = d.x / SLN; r0 = atomicAdd(&hcnt[b0], 1);
            b1i = d.y / SLN; r1 = atomicAdd(&hcnt[b1i], 1);
            b2i = d.z / SLN; r2 = atomicAdd(&hcnt[b2i], 1);
            b3i = d.w / SLN; r3 = atomicAdd(&hcnt[b3i], 1);
        }
        __syncthreads();
        if (tid < 8) hbase[tid] = atomicAdd(&binCnt[tid], hcnt[tid]);
        __syncthreads();
        if (val) {
            binBuf[(size_t)b0 * BCAP + hbase[b0] + r0] = make_int2(d.x, s.x);
            binBuf[(size_t)b1i * BCAP + hbase[b1i] + r1] = make_int2(d.y, s.y);
            binBuf[(size_t)b2i * BCAP + hbase[b2i] + r2] = make_int2(d.z, s.z);
            binBuf[(size_t)b3i * BCAP + hbase[b3i] + r3] = make_int2(d.w, s.w);
        }
    }
}

// ---------------- MFMA GEMM: BM=128, grid (391, TOTN/64); one B-stage per block.
// MODE 1: bias+relu bf16 out; MODE 2: col<128 -> fp8 P2, else bf16 R2.
template <int K, int TOTN, int MODE>
__global__ __launch_bounds__(256) void k_gemm(const unsigned short* __restrict__ A,
                                              const unsigned short* __restrict__ Wf,
                                              const float* __restrict__ bias,
                                              unsigned short* __restrict__ Out,
                                              unsigned char* __restrict__ Pf8) {
    constexpr int KT = K / 32;
    __shared__ unsigned short Bs[K * 64];
    int tid = threadIdx.x;
    int lane = tid & 63, w = tid >> 6;
    int bm = blockIdx.x, nb = blockIdx.y;

    // A fragments (issued before barrier to overlap with B staging)
    int r0 = bm * 128 + w * 32;
    int ra0 = r0 + (lane & 15);
    int ra1 = ra0 + 16;
    if (ra0 >= NN) ra0 = NN - 1;
    if (ra1 >= NN) ra1 = NN - 1;
    const unsigned short* ap0 = A + (size_t)ra0 * K + ((lane >> 4) * 8);
    const unsigned short* ap1 = A + (size_t)ra1 * K + ((lane >> 4) * 8);
    short8 afr0[KT], afr1[KT];
#pragma unroll
    for (int kt = 0; kt < KT; kt++) {
        afr0[kt] = *(const short8*)(ap0 + kt * 32);
        afr1[kt] = *(const short8*)(ap1 + kt * 32);
    }

    // stage this column group's B fragments (K*128 bytes)
    {
        const float4* srcp = (const float4*)(Wf + (size_t)nb * K * 64);
        float4* dsts = (float4*)Bs;
        for (int i = tid; i < K * 8; i += 256) dsts[i] = srcp[i];
    }
    __syncthreads();

    f32x4 acc[2][4];
#pragma unroll
    for (int i = 0; i < 2; i++)
#pragma unroll
        for (int f = 0; f < 4; f++) acc[i][f] = (f32x4){0.f, 0.f, 0.f, 0.f};
#pragma unroll
    for (int kt = 0; kt < KT; kt++) {
#pragma unroll
        for (int f = 0; f < 4; f++) {
            short8 bfr = *(const short8*)&Bs[((kt * 4 + f) * 64 + lane) * 8];
            acc[0][f] = __builtin_amdgcn_mfma_f32_16x16x32_bf16(afr0[kt], bfr, acc[0][f], 0, 0, 0);
            acc[1][f] = __builtin_amdgcn_mfma_f32_16x16x32_bf16(afr1[kt], bfr, acc[1][f], 0, 0, 0);
        }
    }

    int cc = nb * 64 + (lane & 15);
    int rb = r0 + (lane >> 4) * 4;
#pragma unroll
    for (int af = 0; af < 2; af++) {
#pragma unroll
        for (int f = 0; f < 4; f++) {
            int col = cc + f * 16;
            float bv = (MODE == 1) ? bias[col] : 0.f;
#pragma unroll
            for (int r = 0; r < 4; r++) {
                int gr = rb + af * 16 + r;
                if (gr < NN) {
                    float val = acc[af][f][r];
                    if (MODE == 1) {
                        val = fmaxf(val + bv, 0.f);
                        Out[(size_t)gr * TOTN + col] = f2bf(val);
                    } else {  // MODE 2
                        if (col < 128) Pf8[(size_t)gr * 128 + col] = f2e5(val);
                        else           Out[(size_t)gr * 128 + (col - 128)] = f2bf(val);
                    }
                }
            }
        }
    }
}

// ---------------- GEMM3: BM=64, grid 782, K=128 -> G3 [NN][128] ----------------
__global__ __launch_bounds__(256) void k_gemm3(const unsigned short* __restrict__ h2,
                                               const unsigned short* __restrict__ Wf3,
                                               unsigned short* __restrict__ G3) {
    constexpr int KT = 4;  // K = 128
    __shared__ unsigned short Bs[128 * 64];  // 16 KB
    int tid = threadIdx.x;
    int lane = tid & 63, w = tid >> 6;
    int bm = blockIdx.x;

    int ra = bm * 64 + w * 16 + (lane & 15);
    if (ra >= NN) ra = NN - 1;
    const unsigned short* ap = h2 + (size_t)ra * 128 + ((lane >> 4) * 8);
    short8 afr[KT];
#pragma unroll
    for (int kt = 0; kt < KT; kt++) afr[kt] = *(const short8*)(ap + kt * 32);

    int gr0 = bm * 64 + w * 16 + (lane >> 4) * 4;

    for (int nb = 0; nb < 2; nb++) {
        __syncthreads();
        {
            const float4* srcp = (const float4*)(Wf3 + (size_t)nb * 128 * 64);
            float4* dsts = (float4*)Bs;
            for (int i = tid; i < 128 * 8; i += 256) dsts[i] = srcp[i];
        }
        __syncthreads();
        f32x4 acc[4];
#pragma unroll
        for (int f = 0; f < 4; f++) acc[f] = (f32x4){0.f, 0.f, 0.f, 0.f};
#pragma unroll
        for (int kt = 0; kt < KT; kt++) {
#pragma unroll
            for (int f = 0; f < 4; f++) {
                short8 bfr = *(const short8*)&Bs[((kt * 4 + f) * 64 + lane) * 8];
                acc[f] = __builtin_amdgcn_mfma_f32_16x16x32_bf16(afr[kt], bfr, acc[f], 0, 0, 0);
            }
        }
        int cc = nb * 64 + (lane & 15);
#pragma unroll
        for (int f = 0; f < 4; f++) {
#pragma unroll
            for (int r = 0; r < 4; r++) {
                int gr = gr0 + r;
                if (gr < NN) G3[(size_t)gr * 128 + cc + f * 16] = f2bf(acc[f][r]);
            }
        }
    }
}

// ================= gathers: bucket CSR =================

__global__ __launch_bounds__(256) void k_aggx(const int* __restrict__ cnt,
                                              const int* __restrict__ csr,
                                              const unsigned char* __restrict__ xf8,
                                              unsigned short* __restrict__ xcat) {
    int lane = threadIdx.x & 63, wv = threadIdx.x >> 6;
    int node = blockIdx.x * 4 + wv;
    int deg = cnt[node];
    const int* cp = csr + node * CAP;
    int g = lane >> 3, l8 = lane & 7;
    float a[16];
#pragma unroll
    for (int j = 0; j < 16; j++) a[j] = 0.f;
    const unsigned char* base = xf8 + l8 * 16;
    int e = 0;
    for (; e + 16 <= deg; e += 16) {
        int s0 = cp[e + g], s1 = cp[e + 8 + g];
        uint4 u0 = *(const uint4*)(base + (size_t)s0 * 128);
        uint4 u1 = *(const uint4*)(base + (size_t)s1 * 128);
        acc16(a, u0); acc16(a, u1);
    }
    if (e + g < deg) {
        uint4 u = *(const uint4*)(base + (size_t)cp[e + g] * 128);
        acc16(a, u);
    }
    if (e + 8 + g < deg) {
        uint4 u = *(const uint4*)(base + (size_t)cp[e + 8 + g] * 128);
        acc16(a, u);
    }
#pragma unroll
    for (int j = 0; j < 16; j++) {
        a[j] += __shfl_xor(a[j], 8);
        a[j] += __shfl_xor(a[j], 16);
        a[j] += __shfl_xor(a[j], 32);
    }
    if (lane < 8) {
        float inv = 1.f / (float)max(deg, 1);
        unsigned short o[16];
#pragma unroll
        for (int j = 0; j < 16; j++) o[j] = f2bf(a[j] * inv);
        *(short8*)&xcat[(size_t)node * 256 + lane * 16] = *(short8*)&o[0];
        *(short8*)&xcat[(size_t)node * 256 + lane * 16 + 8] = *(short8*)&o[8];
    }
}

__global__ __launch_bounds__(256) void k_agg2(const unsigned char* __restrict__ pf8,
                                              const unsigned short* __restrict__ r2,
                                              const int* __restrict__ cnt,
                                              const int* __restrict__ csr,
                                              const float* __restrict__ c,
                                              unsigned short* __restrict__ h2) {
    int lane = threadIdx.x & 63, wv = threadIdx.x >> 6;
    int node = blockIdx.x * 4 + wv;
    int deg = cnt[node];
    const int* cp = csr + node * CAP;
    int g = lane >> 3, l8 = lane & 7;
    float a[16];
#pragma unroll
    for (int j = 0; j < 16; j++) a[j] = 0.f;
    const unsigned char* base = pf8 + l8 * 16;
    int e = 0;
    for (; e + 16 <= deg; e += 16) {
        int s0 = cp[e + g], s1 = cp[e + 8 + g];
        uint4 u0 = *(const uint4*)(base + (size_t)s0 * 128);
        uint4 u1 = *(const uint4*)(base + (size_t)s1 * 128);
        acc16(a, u0); acc16(a, u1);
    }
    if (e + g < deg) {
        uint4 u = *(const uint4*)(base + (size_t)cp[e + g] * 128);
        acc16(a, u);
    }
    if (e + 8 + g < deg) {
        uint4 u = *(const uint4*)(base + (size_t)cp[e + 8 + g] * 128);
        acc16(a, u);
    }
#pragma unroll
    for (int j = 0; j < 16; j++) {
        a[j] += __shfl_xor(a[j], 8);
        a[j] += __shfl_xor(a[j], 16);
        a[j] += __shfl_xor(a[j], 32);
    }
    if (lane < 8) {
        float inv = 1.f / (float)max(deg, 1);
        short8 rA = *(const short8*)&r2[(size_t)node * 128 + lane * 16];
        short8 rB = *(const short8*)&r2[(size_t)node * 128 + lane * 16 + 8];
        const float* cpb = c + lane * 16;
        unsigned short o[16];
#pragma unroll
        for (int j = 0; j < 8; j++)
            o[j] = f2bf(fmaxf(a[j] * inv + bf2f(rA[j]) + cpb[j], 0.f));
#pragma unroll
        for (int j = 0; j < 8; j++)
            o[8 + j] = f2bf(fmaxf(a[8 + j] * inv + bf2f(rB[j]) + cpb[8 + j], 0.f));
        *(short8*)&h2[(size_t)node * 128 + lane * 16] = *(short8*)&o[0];
        *(short8*)&h2[(size_t)node * 128 + lane * 16 + 8] = *(short8*)&o[8];
    }
}

__global__ __launch_bounds__(256) void k_agg_final(const unsigned short* __restrict__ G,
                                                   const int* __restrict__ cnt,
                                                   const int* __restrict__ csr,
                                                   const float* __restrict__ c,
                                                   const float* __restrict__ Wc,
                                                   const float* __restrict__ bc,
                                                   float* __restrict__ outbuf) {
    int lane = threadIdx.x & 63, wv = threadIdx.x >> 6;
    int node = blockIdx.x * 4 + wv;
    int deg = cnt[node];
    const int* cp = csr + node * CAP;
    int g = lane >> 3, l8 = lane & 7;
    float a[8];
#pragma unroll
    for (int j = 0; j < 8; j++) a[j] = 0.f;
    const unsigned short* base = G + l8 * 8;
    int e = 0;
    for (; e + 32 <= deg; e += 32) {
        int s0 = cp[e + g], s1 = cp[e + 8 + g], s2 = cp[e + 16 + g], s3 = cp[e + 24 + g];
        short8 u0 = *(const short8*)(base + (size_t)s0 * 128);
        short8 u1 = *(const short8*)(base + (size_t)s1 * 128);
        short8 u2 = *(const short8*)(base + (size_t)s2 * 128);
        short8 u3 = *(const short8*)(base + (size_t)s3 * 128);
#pragma unroll
        for (int j = 0; j < 8; j++)
            a[j] += (bf2f(u0[j]) + bf2f(u1[j])) + (bf2f(u2[j]) + bf2f(u3[j]));
    }
    for (; e + 8 <= deg; e += 8) {
        short8 u = *(const short8*)(base + (size_t)cp[e + g] * 128);
#pragma unroll
        for (int j = 0; j < 8; j++) a[j] += bf2f(u[j]);
    }
    if (e + g < deg) {
        short8 u = *(const short8*)(base + (size_t)cp[e + g] * 128);
#pragma unroll
        for (int j = 0; j < 8; j++) a[j] += bf2f(u[j]);
    }
#pragma unroll
    for (int j = 0; j < 8; j++) {
        a[j] += __shfl_xor(a[j], 8);
        a[j] += __shfl_xor(a[j], 16);
        a[j] += __shfl_xor(a[j], 32);
    }
    float l0 = 0.f, l1 = 0.f;
    if (lane < 8) {
        float inv = 1.f / (float)max(deg, 1);
        short8 r = *(const short8*)&G[(size_t)node * 128 + 64 + l8 * 8];
        const float* cpb = c + l8 * 8;
        float v[8];
#pragma unroll
        for (int j = 0; j < 8; j++) v[j] = a[j] * inv + bf2f(r[j]) + cpb[j];
        float* emb = outbuf + 2 * (size_t)NN;
        *(float4*)&emb[(size_t)node * 64 + l8 * 8] = make_float4(v[0], v[1], v[2], v[3]);
        *(float4*)&emb[(size_t)node * 64 + l8 * 8 + 4] = make_float4(v[4], v[5], v[6], v[7]);
        int c0 = l8 * 8;
#pragma unroll
        for (int j = 0; j < 8; j++) {
            l0 += v[j] * Wc[2 * (c0 + j)];
            l1 += v[j] * Wc[2 * (c0 + j) + 1];
        }
    }
    l0 += __shfl_xor(l0, 1); l1 += __shfl_xor(l1, 1);
    l0 += __shfl_xor(l0, 2); l1 += __shfl_xor(l1, 2);
    l0 += __shfl_xor(l0, 4); l1 += __shfl_xor(l1, 4);
    if (lane == 0) {
        outbuf[(size_t)node * 2 + 0] = l0 + bc[0];
        outbuf[(size_t)node * 2 + 1] = l1 + bc[1];
    }
}

extern "C" void kernel_launch(void* const* d_in, const int* in_sizes, int n_in,
                              void* d_out, int out_size, void* d_ws, size_t ws_size,
                              hipStream_t stream) {
    const float* x    = (const float*)d_in[0];
    const int*   ei   = (const int*)d_in[1];
    const float* Wp   = (const float*)d_in[2];
    const float* bp   = (const float*)d_in[3];
    const float* W1l  = (const float*)d_in[4];
    const float* b1l  = (const float*)d_in[5];
    const float* W1r  = (const float*)d_in[6];
    const float* bn1g = (const float*)d_in[7];
    const float* bn1b = (const float*)d_in[8];
    const float* bn1m = (const float*)d_in[9];
    const float* bn1v = (const float*)d_in[10];
    const float* Wsk  = (const float*)d_in[11];
    const float* bsk  = (const float*)d_in[12];
    const float* W2l  = (const float*)d_in[13];
    const float* b2l  = (const float*)d_in[14];
    const float* W2r  = (const float*)d_in[15];
    const float* bn2g = (const float*)d_in[16];
    const float* bn2b = (const float*)d_in[17];
    const float* bn2m = (const float*)d_in[18];
    const float* bn2v = (const float*)d_in[19];
    const float* W3l  = (const float*)d_in[20];
    const float* b3l  = (const float*)d_in[21];
    const float* W3r  = (const float*)d_in[22];
    const float* Wc   = (const float*)d_in[23];
    const float* bc   = (const float*)d_in[24];

    const int* src = ei;
    const int* dst = ei + NE;

    char* ws = (char*)d_ws;
    size_t o = 0;
    auto alloc = [&](size_t b) -> char* {
        char* p = ws + o;
        o = (o + b + 255) & ~(size_t)255;
        return p;
    };
    int* cnt    = (int*)alloc((size_t)NN * 4);
    int* binCnt = (int*)alloc(64);
    int* csr    = (int*)alloc((size_t)NN * CAP * 4);                       // 12.8 MB
    unsigned char*  xf8  = (unsigned char*)alloc((size_t)NN * 128);        // fp8 x (gather src)
    unsigned short* xcat = (unsigned short*)alloc((size_t)NN * 256 * 2);   // [mean1|xb] bf16
    unsigned short* h1   = (unsigned short*)alloc((size_t)NN * 256 * 2);   // bf16 h1
    unsigned char*  pf8  = (unsigned char*)alloc((size_t)NN * 128);        // fp8 P2 (gather src)
    unsigned short* r2   = (unsigned short*)alloc((size_t)NN * 128 * 2);   // bf16 R2
    unsigned short* h2   = (unsigned short*)alloc((size_t)NN * 128 * 2);
    unsigned short* G3   = (unsigned short*)alloc((size_t)NN * 128 * 2);   // [P3|R3]; binBuf aliases
    unsigned short* Wf1  = (unsigned short*)alloc((size_t)256 * 256 * 2);
    unsigned short* Wf2  = (unsigned short*)alloc((size_t)256 * 256 * 2);
    unsigned short* Wf3  = (unsigned short*)alloc((size_t)128 * 128 * 2);
    float* c1 = (float*)alloc(256 * 4);
    float* c2 = (float*)alloc(128 * 4);
    float* c3 = (float*)alloc(64 * 4);
    int2* binBuf = (int2*)G3;  // 6.8MB <= 12.8MB; dead before G3 first written

    float* outbuf = (float*)d_out;  // logits [NN][2] then emb [NN][64]

    // fused prep: xcast + zero cnt + weight folding + edge binning
    hipMemsetAsync(binCnt, 0, 64, stream);
    k_prep_fused<<<7104, 256, 0, stream>>>(x, xcat, xf8, cnt, binCnt, src, dst, binBuf,
                                           Wp, bp, W1l, b1l, W1r, bn1g, bn1b, bn1m, bn1v,
                                           Wsk, bsk, W2l, b2l, W2r, bn2g, bn2b, bn2m, bn2v,
                                           W3l, b3l, W3r, Wf1, Wf2, Wf3, c1, c2, c3);

    // XCD-local scatter into bucket CSR
    k_scatter2<<<1024, 256, 0, stream>>>(binBuf, binCnt, cnt, csr);

    // layer 1: mean(xf8) into xcat cols 0..127 ; h1 = relu([mean|xb] @ Wf1 + c1)
    k_aggx<<<12500, 256, 0, stream>>>(cnt, csr, xf8, xcat);
    k_gemm<256, 256, 1><<<dim3(391, 4), 256, 0, stream>>>(xcat, Wf1, c1, h1, nullptr);

    // layer 2: P2 (fp8) + R2 (bf16) = h1 @ Wf2 ; h2 = relu(mean(P2) + R2 + c2)
    k_gemm<256, 256, 2><<<dim3(391, 4), 256, 0, stream>>>(h1, Wf2, nullptr, r2, pf8);
    k_agg2<<<12500, 256, 0, stream>>>(pf8, r2, cnt, csr, c2, h2);

    // layer 3: [P3|R3] = h2 @ Wf3 (bf16) ; emb = mean(P3)+R3+c3 ; logits fused
    k_gemm3<<<782, 256, 0, stream>>>(h2, Wf3, G3);
    k_agg_final<<<12500, 256, 0, stream>>>(G3, cnt, csr, c3, Wc, bc, outbuf);
}

// Round 18
// 200.086 us; speedup vs baseline: 1.1127x; 1.1127x over previous
//
#include <hip/hip_runtime.h>
#include <hip/hip_fp16.h>

#define NN 50000
#define NE 800000
#define SLN 6250        // NN/8 nodes per XCD bin
#define CAP 64          // csr slots per node (Poisson(16): P(deg>=64) ~ 1e-18)
#define BCAP 106496     // pair capacity per bin
constexpr float EPSV = 1e-5f;

typedef __attribute__((ext_vector_type(8))) short short8;
typedef __attribute__((ext_vector_type(4))) float f32x4;

__device__ __forceinline__ float bf2f(unsigned short u) {
    return __uint_as_float(((unsigned int)u) << 16);
}
__device__ __forceinline__ unsigned short f2bf(float f) {
    unsigned int x = __float_as_uint(f);
    return (unsigned short)((x + 0x7FFFu + ((x >> 16) & 1u)) >> 16);
}
// f32 -> fp8 e5m2 (via fp16, round-to-nearest-even on the mantissa drop)
__device__ __forceinline__ unsigned char f2e5(float f) {
    unsigned short h = __half_as_ushort(__float2half(f));
    unsigned short r = h + 0x7F + ((h >> 8) & 1);
    return (unsigned char)(r >> 8);
}
// accumulate 16 fp8(e5m2) packed in a uint4 into a[0..15]
__device__ __forceinline__ void acc16(float* a, uint4 u) {
#pragma unroll
    for (int q = 0; q < 4; q++) {
        unsigned int x = (q == 0) ? u.x : (q == 1) ? u.y : (q == 2) ? u.z : u.w;
        unsigned int h01 = ((x << 8) & 0xFF00u) | ((x << 16) & 0xFF000000u);
        unsigned int h23 = ((x >> 8) & 0xFF00u) | (x & 0xFF000000u);
        __half2 p01 = *(__half2*)&h01, p23 = *(__half2*)&h23;
        float2 f01 = __half22float2(p01), f23 = __half22float2(p23);
        a[q * 4 + 0] += f01.x; a[q * 4 + 1] += f01.y;
        a[q * 4 + 2] += f23.x; a[q * 4 + 3] += f23.y;
    }
}

// ---------------- edge binning: read edges once, bucket pairs by dst XCD slice ----------------
__global__ __launch_bounds__(256) void k_bin(const int* __restrict__ src,
                                             const int* __restrict__ dst,
                                             int* __restrict__ binCnt,
                                             int2* __restrict__ binBuf) {
    __shared__ int hcnt[8];
    __shared__ int hbase[8];
    int tid = threadIdx.x;
    if (tid < 8) hcnt[tid] = 0;
    __syncthreads();
    int q = blockIdx.x * 256 + tid;
    bool val = q < NE / 4;
    int4 d = make_int4(0, 0, 0, 0), s = make_int4(0, 0, 0, 0);
    int b0 = 0, b1 = 0, b2 = 0, b3 = 0, r0 = 0, r1 = 0, r2 = 0, r3 = 0;
    if (val) {
        d = ((const int4*)dst)[q];
        s = ((const int4*)src)[q];
        b0 = d.x / SLN; r0 = atomicAdd(&hcnt[b0], 1);
        b1 = d.y / SLN; r1 = atomicAdd(&hcnt[b1], 1);
        b2 = d.z / SLN; r2 = atomicAdd(&hcnt[b2], 1);
        b3 = d.w / SLN; r3 = atomicAdd(&hcnt[b3], 1);
    }
    __syncthreads();
    if (tid < 8) hbase[tid] = atomicAdd(&binCnt[tid], hcnt[tid]);
    __syncthreads();
    if (val) {
        binBuf[(size_t)b0 * BCAP + hbase[b0] + r0] = make_int2(d.x, s.x);
        binBuf[(size_t)b1 * BCAP + hbase[b1] + r1] = make_int2(d.y, s.y);
        binBuf[(size_t)b2 * BCAP + hbase[b2] + r2] = make_int2(d.z, s.z);
        binBuf[(size_t)b3 * BCAP + hbase[b3] + r3] = make_int2(d.w, s.w);
    }
}

// ---------------- scatter: blocks on XCD k consume bin k; all writes XCD-L2-local ----------------
__global__ __launch_bounds__(256) void k_scatter2(const int2* __restrict__ binBuf,
                                                  const int* __restrict__ binCnt,
                                                  int* __restrict__ cnt,
                                                  int* __restrict__ csr) {
    int bin = blockIdx.x & 7;
    int lb = blockIdx.x >> 3;
    int n = binCnt[bin];
    const int2* buf = binBuf + (size_t)bin * BCAP;
    for (int i = lb * 256 + threadIdx.x; i < n; i += 128 * 256) {
        int2 p = buf[i];
        int slot = atomicAdd(&cnt[p.x], 1);
        csr[p.x * CAP + slot] = p.y;
    }
}

// ---------------- fused prep: xcast (bf16 + fp8) + cnt/binCnt zero + weight folding ----------------
__device__ void prep1_body(int t, const float* Wp, const float* bp, const float* W1l,
                           const float* b1l, const float* W1r, const float* g, const float* b,
                           const float* m, const float* v, unsigned short* Wf, float* c) {
    int lane = t & 63, f = (t >> 6) & 3, kt = (t >> 8) & 7;
    int nb = t >> 11;
    int col = nb * 64 + f * 16 + (lane & 15);
    int k0 = kt * 32 + (lane >> 4) * 8;
    float A = g[col] * rsqrtf(v[col] + EPSV);
    unsigned short* o = Wf + (size_t)t * 8;
    for (int j = 0; j < 8; j++) {
        int k = k0 + j;
        float w;
        if (k < 128) w = W1l[k * 256 + col] * A;
        else         w = W1r[(k - 128) * 256 + col] * A + Wp[(k - 128) * 256 + col];
        o[j] = f2bf(w);
    }
    if (t < 256) {
        float At = g[t] * rsqrtf(v[t] + EPSV);
        c[t] = b1l[t] * At + (b[t] - m[t] * At) + bp[t];
    }
}

__device__ void prep2_body(int t, const float* Wsk, const float* bsk, const float* W2l,
                           const float* b2l, const float* W2r, const float* g, const float* b,
                           const float* m, const float* v, unsigned short* Wf, float* c) {
    int lane = t & 63, f = (t >> 6) & 3, kt = (t >> 8) & 7, nb = t >> 11;
    int col = nb * 64 + f * 16 + (lane & 15);
    int k0 = kt * 32 + (lane >> 4) * 8;
    unsigned short* o = Wf + (size_t)t * 8;
    if (col < 128) {
        float A = g[col] * rsqrtf(v[col] + EPSV);
        for (int j = 0; j < 8; j++) o[j] = f2bf(W2l[(k0 + j) * 128 + col] * A);
    } else {
        int cc = col - 128;
        float A = g[cc] * rsqrtf(v[cc] + EPSV);
        for (int j = 0; j < 8; j++)
            o[j] = f2bf(W2r[(k0 + j) * 128 + cc] * A + Wsk[(k0 + j) * 128 + cc]);
    }
    if (t < 128) {
        float At = g[t] * rsqrtf(v[t] + EPSV);
        c[t] = b2l[t] * At + (b[t] - m[t] * At) + bsk[t];
    }
}

__device__ void prep3_body(int t, const float* W3l, const float* b3l, const float* W3r,
                           unsigned short* Wf, float* c) {
    int lane = t & 63, f = (t >> 6) & 3, kt = (t >> 8) & 3, nb = t >> 10;
    int col = nb * 64 + f * 16 + (lane & 15);
    int k0 = kt * 32 + (lane >> 4) * 8;
    unsigned short* o = Wf + (size_t)t * 8;
    if (col < 64) {
        for (int j = 0; j < 8; j++) o[j] = f2bf(W3l[(k0 + j) * 64 + col]);
    } else {
        int cc = col - 64;
        for (int j = 0; j < 8; j++) o[j] = f2bf(W3r[(k0 + j) * 64 + cc]);
    }
    if (t < 64) c[t] = b3l[t];
}

__global__ void k_prep_fused(const float* x, unsigned short* xcat, unsigned char* xf8,
                             int* cnt, int* binCnt,
                             const float* Wp, const float* bp,
                             const float* W1l, const float* b1l, const float* W1r,
                             const float* g1, const float* b1, const float* m1, const float* v1,
                             const float* Wsk, const float* bsk,
                             const float* W2l, const float* b2l, const float* W2r,
                             const float* g2, const float* b2, const float* m2, const float* v2,
                             const float* W3l, const float* b3l, const float* W3r,
                             unsigned short* Wf1, unsigned short* Wf2, unsigned short* Wf3,
                             float* c1, float* c2, float* c3) {
    int bb = blockIdx.x;
    if (bb < 6250) {  // xcast + zeroing
        int i = bb * 256 + threadIdx.x;
        if (i < NN / 4) ((int4*)cnt)[i] = make_int4(0, 0, 0, 0);
        if (i < 2) ((int4*)binCnt)[i] = make_int4(0, 0, 0, 0);
        if (i >= NN * 128 / 4) return;
        int r = i >> 5, c4 = (i & 31) * 4;
        float4 v = ((const float4*)x)[i];
        ushort4 u = make_ushort4(f2bf(v.x), f2bf(v.y), f2bf(v.z), f2bf(v.w));
        *(ushort4*)&xcat[(size_t)r * 256 + 128 + c4] = u;
        uchar4 u8 = make_uchar4(f2e5(v.x), f2e5(v.y), f2e5(v.z), f2e5(v.w));
        *(uchar4*)&xf8[(size_t)r * 128 + c4] = u8;
    } else if (bb < 6282) {
        prep1_body((bb - 6250) * 256 + threadIdx.x, Wp, bp, W1l, b1l, W1r, g1, b1, m1, v1, Wf1, c1);
    } else if (bb < 6314) {
        prep2_body((bb - 6282) * 256 + threadIdx.x, Wsk, bsk, W2l, b2l, W2r, g2, b2, m2, v2, Wf2, c2);
    } else {
        prep3_body((bb - 6314) * 256 + threadIdx.x, W3l, b3l, W3r, Wf3, c3);
    }
}

// ---------------- fused GEMM1+GEMM2: h1 tile lives in LDS, never touches global.
// BM=64, 4 waves x 16 rows. Phase 1: h1 = relu([mean|xb]@Wf1 + c1) -> LDS tile.
// Phase 2: [P2|R2] = h1_tile @ Wf2 -> pf8 (cols<128) / r2 (cols>=128).
__global__ __launch_bounds__(256) void k_gemm12(const unsigned short* __restrict__ xcat,
                                                const unsigned short* __restrict__ Wf1,
                                                const float* __restrict__ c1,
                                                const unsigned short* __restrict__ Wf2,
                                                unsigned short* __restrict__ r2,
                                                unsigned char* __restrict__ pf8) {
    constexpr int KT = 8;      // K = 256
    constexpr int HS = 272;    // hs row stride (shorts): 544B, 16B-aligned rows
    __shared__ unsigned short Bs[256 * 64];  // 32 KB
    __shared__ unsigned short hs[64 * HS];   // 34.8 KB
    int tid = threadIdx.x;
    int lane = tid & 63, w = tid >> 6;
    int bm = blockIdx.x;
    int rbase = bm * 64 + w * 16;

    // phase-1 A fragments from xcat [mean|xb]
    int ra = rbase + (lane & 15);
    if (ra >= NN) ra = NN - 1;
    const unsigned short* ap = xcat + (size_t)ra * 256 + ((lane >> 4) * 8);
    short8 afr[KT];
#pragma unroll
    for (int kt = 0; kt < KT; kt++) afr[kt] = *(const short8*)(ap + kt * 32);

    int hrow0 = w * 16 + (lane >> 4) * 4;

    // phase 1: h1 tile -> hs
    for (int nb = 0; nb < 4; nb++) {
        __syncthreads();
        {
            const float4* srcp = (const float4*)(Wf1 + (size_t)nb * 256 * 64);
            float4* dsts = (float4*)Bs;
            for (int i = tid; i < 256 * 8; i += 256) dsts[i] = srcp[i];
        }
        __syncthreads();
        f32x4 acc[4];
#pragma unroll
        for (int f = 0; f < 4; f++) acc[f] = (f32x4){0.f, 0.f, 0.f, 0.f};
#pragma unroll
        for (int kt = 0; kt < KT; kt++) {
#pragma unroll
            for (int f = 0; f < 4; f++) {
                short8 bfr = *(const short8*)&Bs[((kt * 4 + f) * 64 + lane) * 8];
                acc[f] = __builtin_amdgcn_mfma_f32_16x16x32_bf16(afr[kt], bfr, acc[f], 0, 0, 0);
            }
        }
        int cc = nb * 64 + (lane & 15);
#pragma unroll
        for (int f = 0; f < 4; f++) {
            int col = cc + f * 16;
            float bv = c1[col];
#pragma unroll
            for (int r = 0; r < 4; r++) {
                float val = fmaxf(acc[f][r] + bv, 0.f);
                hs[(hrow0 + r) * HS + col] = f2bf(val);
            }
        }
    }

    // phase-2 A fragments from this wave's own hs rows (wave-local: no sync needed)
    short8 a2[KT];
    {
        const unsigned short* hp = &hs[(w * 16 + (lane & 15)) * HS + ((lane >> 4) * 8)];
#pragma unroll
        for (int kt = 0; kt < KT; kt++) a2[kt] = *(const short8*)(hp + kt * 32);
    }

    int gr0 = rbase + (lane >> 4) * 4;
    // phase 2: [P2|R2]
    for (int nb = 0; nb < 4; nb++) {
        __syncthreads();
        {
            const float4* srcp = (const float4*)(Wf2 + (size_t)nb * 256 * 64);
            float4* dsts = (float4*)Bs;
            for (int i = tid; i < 256 * 8; i += 256) dsts[i] = srcp[i];
        }
        __syncthreads();
        f32x4 acc[4];
#pragma unroll
        for (int f = 0; f < 4; f++) acc[f] = (f32x4){0.f, 0.f, 0.f, 0.f};
#pragma unroll
        for (int kt = 0; kt < KT; kt++) {
#pragma unroll
            for (int f = 0; f < 4; f++) {
                short8 bfr = *(const short8*)&Bs[((kt * 4 + f) * 64 + lane) * 8];
                acc[f] = __builtin_amdgcn_mfma_f32_16x16x32_bf16(a2[kt], bfr, acc[f], 0, 0, 0);
            }
        }
        int cc = nb * 64 + (lane & 15);
#pragma unroll
        for (int f = 0; f < 4; f++) {
            int col = cc + f * 16;
#pragma unroll
            for (int r = 0; r < 4; r++) {
                int gr = gr0 + r;
                if (gr < NN) {
                    float val = acc[f][r];
                    if (col < 128) pf8[(size_t)gr * 128 + col] = f2e5(val);
                    else           r2[(size_t)gr * 128 + (col - 128)] = f2bf(val);
                }
            }
        }
    }
}

// ---------------- MFMA GEMM (layer 3): BM=128, A-frags in regs, serial col-group loop
template <int K, int TOTN, int MODE>
__global__ __launch_bounds__(256) void k_gemm(const unsigned short* __restrict__ A,
                                              const unsigned short* __restrict__ Wf,
                                              const float* __restrict__ bias,
                                              unsigned short* __restrict__ Out,
                                              unsigned char* __restrict__ Pf8) {
    constexpr int KT = K / 32;
    constexpr int NB = TOTN / 64;
    __shared__ unsigned short Bs[K * 64];
    int tid = threadIdx.x;
    int lane = tid & 63, w = tid >> 6;
    int bm = blockIdx.x;

    int r0 = bm * 128 + w * 32;
    int ra0 = r0 + (lane & 15);
    int ra1 = ra0 + 16;
    if (ra0 >= NN) ra0 = NN - 1;
    if (ra1 >= NN) ra1 = NN - 1;
    const unsigned short* ap0 = A + (size_t)ra0 * K + ((lane >> 4) * 8);
    const unsigned short* ap1 = A + (size_t)ra1 * K + ((lane >> 4) * 8);
    short8 afr0[KT], afr1[KT];
#pragma unroll
    for (int kt = 0; kt < KT; kt++) {
        afr0[kt] = *(const short8*)(ap0 + kt * 32);
        afr1[kt] = *(const short8*)(ap1 + kt * 32);
    }

    int rb = r0 + (lane >> 4) * 4;

    for (int nb = 0; nb < NB; nb++) {
        __syncthreads();
        {
            const float4* srcp = (const float4*)(Wf + (size_t)nb * K * 64);
            float4* dsts = (float4*)Bs;
            for (int i = tid; i < K * 8; i += 256) dsts[i] = srcp[i];
        }
        __syncthreads();

        f32x4 acc[2][4];
#pragma unroll
        for (int i = 0; i < 2; i++)
#pragma unroll
            for (int f = 0; f < 4; f++) acc[i][f] = (f32x4){0.f, 0.f, 0.f, 0.f};
#pragma unroll
        for (int kt = 0; kt < KT; kt++) {
#pragma unroll
            for (int f = 0; f < 4; f++) {
                short8 bfr = *(const short8*)&Bs[((kt * 4 + f) * 64 + lane) * 8];
                acc[0][f] = __builtin_amdgcn_mfma_f32_16x16x32_bf16(afr0[kt], bfr, acc[0][f], 0, 0, 0);
                acc[1][f] = __builtin_amdgcn_mfma_f32_16x16x32_bf16(afr1[kt], bfr, acc[1][f], 0, 0, 0);
            }
        }

        int cc = nb * 64 + (lane & 15);
#pragma unroll
        for (int af = 0; af < 2; af++) {
#pragma unroll
            for (int f = 0; f < 4; f++) {
#pragma unroll
                for (int r = 0; r < 4; r++) {
                    int gr = rb + af * 16 + r;
                    if (gr < NN) {
                        float val = acc[af][f][r];
                        Out[(size_t)gr * TOTN + cc + f * 16] = f2bf(val);
                    }
                }
            }
        }
    }
}

// ================= gathers: bucket CSR =================

// layer-1: mean of xf8 (fp8 [NN][128B]) -> xcat cols 0..127 (bf16). 8 lanes/edge, 16B fp8 each.
__global__ __launch_bounds__(256) void k_aggx(const int* __restrict__ cnt,
                                              const int* __restrict__ csr,
                                              const unsigned char* __restrict__ xf8,
                                              unsigned short* __restrict__ xcat) {
    int lane = threadIdx.x & 63, wv = threadIdx.x >> 6;
    int node = blockIdx.x * 4 + wv;
    int deg = cnt[node];
    const int* cp = csr + node * CAP;
    int g = lane >> 3, l8 = lane & 7;
    float a[16];
#pragma unroll
    for (int j = 0; j < 16; j++) a[j] = 0.f;
    const unsigned char* base = xf8 + l8 * 16;
    int e = 0;
    for (; e + 16 <= deg; e += 16) {
        int s0 = cp[e + g], s1 = cp[e + 8 + g];
        uint4 u0 = *(const uint4*)(base + (size_t)s0 * 128);
        uint4 u1 = *(const uint4*)(base + (size_t)s1 * 128);
        acc16(a, u0); acc16(a, u1);
    }
    if (e + g < deg) {
        uint4 u = *(const uint4*)(base + (size_t)cp[e + g] * 128);
        acc16(a, u);
    }
    if (e + 8 + g < deg) {
        uint4 u = *(const uint4*)(base + (size_t)cp[e + 8 + g] * 128);
        acc16(a, u);
    }
#pragma unroll
    for (int j = 0; j < 16; j++) {
        a[j] += __shfl_xor(a[j], 8);
        a[j] += __shfl_xor(a[j], 16);
        a[j] += __shfl_xor(a[j], 32);
    }
    if (lane < 8) {
        float inv = 1.f / (float)max(deg, 1);
        unsigned short o[16];
#pragma unroll
        for (int j = 0; j < 16; j++) o[j] = f2bf(a[j] * inv);
        *(short8*)&xcat[(size_t)node * 256 + lane * 16] = *(short8*)&o[0];
        *(short8*)&xcat[(size_t)node * 256 + lane * 16 + 8] = *(short8*)&o[8];
    }
}

// layer-2: h2 = relu(mean(gather pf8) + r2 + c); pf8 [NN][128B], r2 bf16 [NN][128]
__global__ __launch_bounds__(256) void k_agg2(const unsigned char* __restrict__ pf8,
                                              const unsigned short* __restrict__ r2,
                                              const int* __restrict__ cnt,
                                              const int* __restrict__ csr,
                                              const float* __restrict__ c,
                                              unsigned short* __restrict__ h2) {
    int lane = threadIdx.x & 63, wv = threadIdx.x >> 6;
    int node = blockIdx.x * 4 + wv;
    int deg = cnt[node];
    const int* cp = csr + node * CAP;
    int g = lane >> 3, l8 = lane & 7;
    float a[16];
#pragma unroll
    for (int j = 0; j < 16; j++) a[j] = 0.f;
    const unsigned char* base = pf8 + l8 * 16;
    int e = 0;
    for (; e + 16 <= deg; e += 16) {
        int s0 = cp[e + g], s1 = cp[e + 8 + g];
        uint4 u0 = *(const uint4*)(base + (size_t)s0 * 128);
        uint4 u1 = *(const uint4*)(base + (size_t)s1 * 128);
        acc16(a, u0); acc16(a, u1);
    }
    if (e + g < deg) {
        uint4 u = *(const uint4*)(base + (size_t)cp[e + g] * 128);
        acc16(a, u);
    }
    if (e + 8 + g < deg) {
        uint4 u = *(const uint4*)(base + (size_t)cp[e + 8 + g] * 128);
        acc16(a, u);
    }
#pragma unroll
    for (int j = 0; j < 16; j++) {
        a[j] += __shfl_xor(a[j], 8);
        a[j] += __shfl_xor(a[j], 16);
        a[j] += __shfl_xor(a[j], 32);
    }
    if (lane < 8) {
        float inv = 1.f / (float)max(deg, 1);
        short8 rA = *(const short8*)&r2[(size_t)node * 128 + lane * 16];
        short8 rB = *(const short8*)&r2[(size_t)node * 128 + lane * 16 + 8];
        const float* cpb = c + lane * 16;
        unsigned short o[16];
#pragma unroll
        for (int j = 0; j < 8; j++)
            o[j] = f2bf(fmaxf(a[j] * inv + bf2f(rA[j]) + cpb[j], 0.f));
#pragma unroll
        for (int j = 0; j < 8; j++)
            o[8 + j] = f2bf(fmaxf(a[8 + j] * inv + bf2f(rB[j]) + cpb[8 + j], 0.f));
        *(short8*)&h2[(size_t)node * 128 + lane * 16] = *(short8*)&o[0];
        *(short8*)&h2[(size_t)node * 128 + lane * 16 + 8] = *(short8*)&o[8];
    }
}

// layer-3: emb = mean(gather G.P) + G.R + c (f32); logits fused. G bf16 [NN][128]
__global__ __launch_bounds__(256) void k_agg_final(const unsigned short* __restrict__ G,
                                                   const int* __restrict__ cnt,
                                                   const int* __restrict__ csr,
                                                   const float* __restrict__ c,
                                                   const float* __restrict__ Wc,
                                                   const float* __restrict__ bc,
                                                   float* __restrict__ outbuf) {
    int lane = threadIdx.x & 63, wv = threadIdx.x >> 6;
    int node = blockIdx.x * 4 + wv;
    int deg = cnt[node];
    const int* cp = csr + node * CAP;
    int g = lane >> 3, l8 = lane & 7;
    float a[8];
#pragma unroll
    for (int j = 0; j < 8; j++) a[j] = 0.f;
    const unsigned short* base = G + l8 * 8;
    int e = 0;
    for (; e + 32 <= deg; e += 32) {
        int s0 = cp[e + g], s1 = cp[e + 8 + g], s2 = cp[e + 16 + g], s3 = cp[e + 24 + g];
        short8 u0 = *(const short8*)(base + (size_t)s0 * 128);
        short8 u1 = *(const short8*)(base + (size_t)s1 * 128);
        short8 u2 = *(const short8*)(base + (size_t)s2 * 128);
        short8 u3 = *(const short8*)(base + (size_t)s3 * 128);
#pragma unroll
        for (int j = 0; j < 8; j++)
            a[j] += (bf2f(u0[j]) + bf2f(u1[j])) + (bf2f(u2[j]) + bf2f(u3[j]));
    }
    for (; e + 8 <= deg; e += 8) {
        short8 u = *(const short8*)(base + (size_t)cp[e + g] * 128);
#pragma unroll
        for (int j = 0; j < 8; j++) a[j] += bf2f(u[j]);
    }
    if (e + g < deg) {
        short8 u = *(const short8*)(base + (size_t)cp[e + g] * 128);
#pragma unroll
        for (int j = 0; j < 8; j++) a[j] += bf2f(u[j]);
    }
#pragma unroll
    for (int j = 0; j < 8; j++) {
        a[j] += __shfl_xor(a[j], 8);
        a[j] += __shfl_xor(a[j], 16);
        a[j] += __shfl_xor(a[j], 32);
    }
    float l0 = 0.f, l1 = 0.f;
    if (lane < 8) {
        float inv = 1.f / (float)max(deg, 1);
        short8 r = *(const short8*)&G[(size_t)node * 128 + 64 + l8 * 8];
        const float* cpb = c + l8 * 8;
        float v[8];
#pragma unroll
        for (int j = 0; j < 8; j++) v[j] = a[j] * inv + bf2f(r[j]) + cpb[j];
        float* emb = outbuf + 2 * (size_t)NN;
        *(float4*)&emb[(size_t)node * 64 + l8 * 8] = make_float4(v[0], v[1], v[2], v[3]);
        *(float4*)&emb[(size_t)node * 64 + l8 * 8 + 4] = make_float4(v[4], v[5], v[6], v[7]);
        int c0 = l8 * 8;
#pragma unroll
        for (int j = 0; j < 8; j++) {
            l0 += v[j] * Wc[2 * (c0 + j)];
            l1 += v[j] * Wc[2 * (c0 + j) + 1];
        }
    }
    l0 += __shfl_xor(l0, 1); l1 += __shfl_xor(l1, 1);
    l0 += __shfl_xor(l0, 2); l1 += __shfl_xor(l1, 2);
    l0 += __shfl_xor(l0, 4); l1 += __shfl_xor(l1, 4);
    if (lane == 0) {
        outbuf[(size_t)node * 2 + 0] = l0 + bc[0];
        outbuf[(size_t)node * 2 + 1] = l1 + bc[1];
    }
}

extern "C" void kernel_launch(void* const* d_in, const int* in_sizes, int n_in,
                              void* d_out, int out_size, void* d_ws, size_t ws_size,
                              hipStream_t stream) {
    const float* x    = (const float*)d_in[0];
    const int*   ei   = (const int*)d_in[1];
    const float* Wp   = (const float*)d_in[2];
    const float* bp   = (const float*)d_in[3];
    const float* W1l  = (const float*)d_in[4];
    const float* b1l  = (const float*)d_in[5];
    const float* W1r  = (const float*)d_in[6];
    const float* bn1g = (const float*)d_in[7];
    const float* bn1b = (const float*)d_in[8];
    const float* bn1m = (const float*)d_in[9];
    const float* bn1v = (const float*)d_in[10];
    const float* Wsk  = (const float*)d_in[11];
    const float* bsk  = (const float*)d_in[12];
    const float* W2l  = (const float*)d_in[13];
    const float* b2l  = (const float*)d_in[14];
    const float* W2r  = (const float*)d_in[15];
    const float* bn2g = (const float*)d_in[16];
    const float* bn2b = (const float*)d_in[17];
    const float* bn2m = (const float*)d_in[18];
    const float* bn2v = (const float*)d_in[19];
    const float* W3l  = (const float*)d_in[20];
    const float* b3l  = (const float*)d_in[21];
    const float* W3r  = (const float*)d_in[22];
    const float* Wc   = (const float*)d_in[23];
    const float* bc   = (const float*)d_in[24];

    const int* src = ei;
    const int* dst = ei + NE;

    char* ws = (char*)d_ws;
    size_t o = 0;
    auto alloc = [&](size_t b) -> char* {
        char* p = ws + o;
        o = (o + b + 255) & ~(size_t)255;
        return p;
    };
    int* cnt    = (int*)alloc((size_t)NN * 4);
    int* binCnt = (int*)alloc(64);
    int* csr    = (int*)alloc((size_t)NN * CAP * 4);                       // 12.8 MB
    unsigned char*  xf8  = (unsigned char*)alloc((size_t)NN * 128);        // fp8 x (gather src)
    unsigned short* xcat = (unsigned short*)alloc((size_t)NN * 256 * 2);   // [mean1|xb] bf16
    unsigned char*  pf8  = (unsigned char*)alloc((size_t)NN * 128);        // fp8 P2 (gather src)
    unsigned short* r2   = (unsigned short*)alloc((size_t)NN * 128 * 2);   // bf16 R2
    unsigned short* h2   = (unsigned short*)alloc((size_t)NN * 128 * 2);
    unsigned short* G3   = (unsigned short*)alloc((size_t)NN * 128 * 2);   // [P3|R3]; binBuf aliases
    unsigned short* Wf1  = (unsigned short*)alloc((size_t)256 * 256 * 2);
    unsigned short* Wf2  = (unsigned short*)alloc((size_t)256 * 256 * 2);
    unsigned short* Wf3  = (unsigned short*)alloc((size_t)128 * 128 * 2);
    float* c1 = (float*)alloc(256 * 4);
    float* c2 = (float*)alloc(128 * 4);
    float* c3 = (float*)alloc(64 * 4);
    int2* binBuf = (int2*)G3;  // 8*BCAP*8B = 6.8MB <= 12.8MB; dead before G3 first written

    float* outbuf = (float*)d_out;  // logits [NN][2] then emb [NN][64]

    // fused prep: xcast (bf16 + fp8) + zero cnt/binCnt + weight folding
    k_prep_fused<<<6322, 256, 0, stream>>>(x, xcat, xf8, cnt, binCnt,
                                           Wp, bp, W1l, b1l, W1r, bn1g, bn1b, bn1m, bn1v,
                                           Wsk, bsk, W2l, b2l, W2r, bn2g, bn2b, bn2m, bn2v,
                                           W3l, b3l, W3r, Wf1, Wf2, Wf3, c1, c2, c3);

    // CSR build: bin pairs by dst XCD slice, then XCD-local scatter into bucket CSR
    k_bin<<<782, 256, 0, stream>>>(src, dst, binCnt, binBuf);
    k_scatter2<<<1024, 256, 0, stream>>>(binBuf, binCnt, cnt, csr);

    // layer 1: mean(xf8) into xcat cols 0..127
    k_aggx<<<12500, 256, 0, stream>>>(cnt, csr, xf8, xcat);

    // layers 1+2 fused GEMM: h1 in LDS; emits P2 (fp8) + R2 (bf16)
    k_gemm12<<<782, 256, 0, stream>>>(xcat, Wf1, c1, Wf2, r2, pf8);
    k_agg2<<<12500, 256, 0, stream>>>(pf8, r2, cnt, csr, c2, h2);

    // layer 3: [P3|R3] = h2 @ Wf3 (bf16) ; emb = mean(P3)+R3+c3 ; logits fused
    k_gemm<128, 128, 0><<<391, 256, 0, stream>>>(h2, Wf3, nullptr, G3, nullptr);
    k_agg_final<<<12500, 256, 0, stream>>>(G3, cnt, csr, c3, Wc, bc, outbuf);
}